// Round 1
// baseline (1564.278 us; speedup 1.0000x reference)
//
#include <hip/hip_runtime.h>
#include <math.h>

#define NCB 4
#define NE 1024
#define DIM 64
#define BQ 8
#define HH 128
#define WW 128
#define NPIX (BQ*HH*WW)        // 131072
#define CHUNK 128
#define NBLOCKS (NPIX/64)      // 2048
#define MSE_DENOM 8388608.0f   // NPIX*DIM
#define EPSF 1e-5f

// ---------------- kernel 0: per-code squared norms ----------------
__global__ __launch_bounds__(64) void rvq_norms(const float* __restrict__ cb,
                                                float* __restrict__ norms) {
    int code = blockIdx.x * 64 + threadIdx.x;  // 0..4095
    const float4* row = reinterpret_cast<const float4*>(cb + (size_t)code * DIM);
    float s0 = 0.f, s1 = 0.f, s2 = 0.f, s3 = 0.f;
#pragma unroll
    for (int k = 0; k < 16; ++k) {
        float4 v = row[k];
        s0 = fmaf(v.x, v.x, s0); s1 = fmaf(v.y, v.y, s1);
        s2 = fmaf(v.z, v.z, s2); s3 = fmaf(v.w, v.w, s3);
    }
    norms[code] = (s0 + s1) + (s2 + s3);
}

// ---------------- kernel 1: main RVQ ----------------
// block = 256 threads = 4 waves; 64 pixels per block (contiguous in x).
// thread (p,q): pixel p of the block, code partition q (codes j%4==q).
__global__ __launch_bounds__(256) void rvq_main(
    const float* __restrict__ z, const float* __restrict__ cb,
    const float* __restrict__ norms,
    float* __restrict__ out_zq, float* __restrict__ out_idx,
    unsigned* __restrict__ hist, float* __restrict__ msePartial)
{
    __shared__ float sE[CHUNK * DIM];   // 32 KB codebook chunk
    __shared__ float sN[CHUNK];
    __shared__ float sCD[256];
    __shared__ int   sCI[256];
    __shared__ int   sBest[64];

    const int tid = threadIdx.x;
    const int p = tid & 63, q = tid >> 6;
    const int bid = blockIdx.x;
    const int b = bid >> 8;
    const int rem = bid & 255;
    const int y = rem >> 1;
    const int x = ((rem & 1) << 6) + p;
    const size_t zbase = (size_t)b * DIM * HH * WW + (size_t)y * WW + x;

    float r[DIM];
#pragma unroll
    for (int c = 0; c < DIM; ++c) r[c] = z[zbase + (size_t)c * (HH * WW)];

    for (int i = 0; i < NCB; ++i) {
        const float* cbi = cb + (size_t)i * NE * DIM;
        float bd = 3.4e38f; int bidx = 0;

        for (int c0 = 0; c0 < NE; c0 += CHUNK) {
            __syncthreads();  // previous chunk consumed
            {   // cooperative staging: 128 codes x 64 floats, coalesced float4
                const float4* src = reinterpret_cast<const float4*>(cbi + (size_t)c0 * DIM);
                float4* dst = reinterpret_cast<float4*>(sE);
#pragma unroll
                for (int k = 0; k < 8; ++k) dst[tid + k * 256] = src[tid + k * 256];
                if (tid < CHUNK) sN[tid] = norms[i * NE + c0 + tid];
            }
            __syncthreads();

            // each wave walks the same code sequence -> LDS broadcast reads
            for (int j = q; j < CHUNK; j += 4) {
                const float4* e = reinterpret_cast<const float4*>(sE + j * DIM);
                float d0 = 0.f, d1 = 0.f, d2 = 0.f, d3 = 0.f;
#pragma unroll
                for (int k = 0; k < 16; ++k) {
                    float4 ev = e[k];
                    d0 = fmaf(r[4 * k + 0], ev.x, d0);
                    d1 = fmaf(r[4 * k + 1], ev.y, d1);
                    d2 = fmaf(r[4 * k + 2], ev.z, d2);
                    d3 = fmaf(r[4 * k + 3], ev.w, d3);
                }
                float dist = sN[j] - 2.0f * ((d0 + d1) + (d2 + d3));
                if (dist < bd) { bd = dist; bidx = c0 + j; }  // first-min within partition
            }
        }

        // cross-wave argmin reduce, (dist, idx) lexicographic for jnp.argmin semantics
        sCD[tid] = bd; sCI[tid] = bidx;
        __syncthreads();
        if (q == 0) {
            float d = sCD[p]; int ix = sCI[p];
#pragma unroll
            for (int qq = 1; qq < 4; ++qq) {
                float d2 = sCD[p + 64 * qq]; int i2 = sCI[p + 64 * qq];
                if (d2 < d || (d2 == d && i2 < ix)) { d = d2; ix = i2; }
            }
            sBest[p] = ix;
        }
        __syncthreads();
        int ix = sBest[p];

        // residual update (all threads keep full r)
        const float4* e = reinterpret_cast<const float4*>(cbi + (size_t)ix * DIM);
#pragma unroll
        for (int k = 0; k < 16; ++k) {
            float4 ev = e[k];
            r[4 * k + 0] -= ev.x; r[4 * k + 1] -= ev.y;
            r[4 * k + 2] -= ev.z; r[4 * k + 3] -= ev.w;
        }

        if (q == 0) {
            // index output: (b, h, w, ph*4+pw, cb)
            int hh = y >> 2, ww = x >> 2, pp = ((y & 3) << 2) + (x & 3);
            size_t off = (size_t)b * 65536 + (size_t)hh * 2048 + (size_t)ww * 64 + pp * 4 + i;
            out_idx[off] = (float)ix;
            atomicAdd(&hist[i * NE + ix], 1u);
            // MSE contribution: (z_q - r_old)^2 = r_new^2
            float s = 0.f;
#pragma unroll
            for (int c = 0; c < DIM; ++c) s = fmaf(r[c], r[c], s);
#pragma unroll
            for (int d_ = 32; d_ > 0; d_ >>= 1) s += __shfl_down(s, d_, 64);
            if (p == 0) msePartial[i * NBLOCKS + bid] = s;
        }
        __syncthreads();
    }

    // z_q = z - r_final (telescoped straight-through sum); wave 0 writes, coalesced
    if (q == 0) {
#pragma unroll
        for (int c = 0; c < DIM; ++c) {
            size_t o = zbase + (size_t)c * (HH * WW);
            out_zq[o] = z[o] - r[c];
        }
    }
}

// ---------------- kernel 2: deterministic loss finalize ----------------
__global__ __launch_bounds__(1024) void rvq_finalize(
    const unsigned* __restrict__ hist, const float* __restrict__ msePartial,
    float* __restrict__ out_loss)
{
    __shared__ float red[1024];
    int t = threadIdx.x;
    float loss = 0.f;
    for (int i = 0; i < NCB; ++i) {
        // usage entropy: probs = (cnt+eps)/(131072+eps*1024); H=-sum p*log(p+eps)
        float cnt = (float)hist[i * NE + t];
        float prob = (cnt + EPSF) / (131072.0f + EPSF * 1024.0f);
        red[t] = -prob * logf(prob + EPSF);
        __syncthreads();
        for (int s = 512; s > 0; s >>= 1) { if (t < s) red[t] += red[t + s]; __syncthreads(); }
        float entropy = red[0];
        __syncthreads();
        // mse sum
        red[t] = msePartial[i * NBLOCKS + t] + msePartial[i * NBLOCKS + 1024 + t];
        __syncthreads();
        for (int s = 512; s > 0; s >>= 1) { if (t < s) red[t] += red[t + s]; __syncthreads(); }
        float mse_sum = red[0];
        __syncthreads();
        loss += 0.25f * (mse_sum / MSE_DENOM) + 0.01f * (logf(1024.0f) - entropy);
    }
    if (t == 0) out_loss[0] = loss;
}

extern "C" void kernel_launch(void* const* d_in, const int* in_sizes, int n_in,
                              void* d_out, int out_size, void* d_ws, size_t ws_size,
                              hipStream_t stream) {
    const float* z  = (const float*)d_in[0];
    const float* cb = (const float*)d_in[1];

    float* out      = (float*)d_out;
    float* out_zq   = out;                    // 8388608
    float* out_loss = out + 8388608;          // 1
    float* out_idx  = out + 8388609;          // 524288 (indices as float)

    unsigned* hist       = (unsigned*)d_ws;                       // 4*1024 u32 = 16 KB
    float*    norms      = (float*)((char*)d_ws + 16384);         // 4*1024 f32 = 16 KB
    float*    msePartial = (float*)((char*)d_ws + 32768);         // 4*2048 f32 = 32 KB

    hipMemsetAsync(d_ws, 0, 16384, stream);   // zero histogram every call (deterministic)
    rvq_norms<<<64, 64, 0, stream>>>(cb, norms);
    rvq_main<<<NBLOCKS, 256, 0, stream>>>(z, cb, norms, out_zq, out_idx, hist, msePartial);
    rvq_finalize<<<1, 1024, 0, stream>>>(hist, msePartial, out_loss);
}